// Round 4
// baseline (514.294 us; speedup 1.0000x reference)
//
#include <hip/hip_runtime.h>
#include <hip/hip_fp16.h>

#define NPTS 25          // 5*5
#define CCH 256
#define HH 135
#define WW 240
#define HWP (HH * WW)    // 32400
#define NV4 (HWP / 4)    // 8100 float4 per plane
#define NB 8
#define NN 1024

// ---------------------------------------------------------------------------
// One block per (b, c); plane staged fp16 in LDS (64,800 B -> 2 blocks/CU).
// Lesson r0-r3: main loop is VALU-dominated (45% busy, ~110 ops/point) because
// the p-fast mapping re-derives the full sampling math for every point.
// Restructure: thread t owns ROI n = t for all 25 points. The bilinear math is
// separable per-axis (valid = vy*vx folds into Hy=vy*hy etc.), so each thread
// computes two 5-entry tables ONCE (~140 ops), and the fully-unrolled 25-point
// loop is ~20 ops/point: unpack offsets + 4 ds_read_u16 + 4 cvt + 4 mul+fma.
// Stores become per-lane 100-B runs at 25.6 KB stride: mitigated by packing
// 4 results into float4 stores (6 x dwordx4 + 1 dword per thread); runs from
// consecutive c-blocks are contiguous, so L2 merges them before HBM writeback.
// ---------------------------------------------------------------------------
__global__ __launch_bounds__(1024, 8) void roi_nmajor(const float* __restrict__ fm,
                                                      const float* __restrict__ cand,
                                                      float* __restrict__ out) {
    __shared__ __half plane[HWP];   // 64,800 bytes

    int blk = blockIdx.x;           // 0..2047
    int c   = blk & (CCH - 1);
    int b   = blk >> 8;
    int t   = threadIdx.x;          // 0..1023  == ROI index n

    // ---- stage plane (b,c) into LDS as fp16 (r3-verified structure) ----
    const float4* src = (const float4*)(fm + ((size_t)b * CCH + c) * HWP);
    {
        float4 v0 = src[t];
        float4 v1 = src[1024 + t];
        float4 v2 = src[2048 + t];
        float4 v3 = src[3072 + t];
        __half2* d;
        d = (__half2*)(plane + (t) * 4);
        d[0] = __half2(__float2half(v0.x), __float2half(v0.y));
        d[1] = __half2(__float2half(v0.z), __float2half(v0.w));
        d = (__half2*)(plane + (1024 + t) * 4);
        d[0] = __half2(__float2half(v1.x), __float2half(v1.y));
        d[1] = __half2(__float2half(v1.z), __float2half(v1.w));
        d = (__half2*)(plane + (2048 + t) * 4);
        d[0] = __half2(__float2half(v2.x), __float2half(v2.y));
        d[1] = __half2(__float2half(v2.z), __float2half(v2.w));
        d = (__half2*)(plane + (3072 + t) * 4);
        d[0] = __half2(__float2half(v3.x), __float2half(v3.y));
        d[1] = __half2(__float2half(v3.z), __float2half(v3.w));

        float4 v4 = src[4096 + t];
        float4 v5 = src[5120 + t];
        float4 v6 = src[6144 + t];
        bool last = (t < NV4 - 7168);   // t < 932
        float4 v7 = last ? src[7168 + t] : make_float4(0.f, 0.f, 0.f, 0.f);
        d = (__half2*)(plane + (4096 + t) * 4);
        d[0] = __half2(__float2half(v4.x), __float2half(v4.y));
        d[1] = __half2(__float2half(v4.z), __float2half(v4.w));
        d = (__half2*)(plane + (5120 + t) * 4);
        d[0] = __half2(__float2half(v5.x), __float2half(v5.y));
        d[1] = __half2(__float2half(v5.z), __float2half(v5.w));
        d = (__half2*)(plane + (6144 + t) * 4);
        d[0] = __half2(__float2half(v6.x), __float2half(v6.y));
        d[1] = __half2(__float2half(v6.z), __float2half(v6.w));
        if (last) {
            d = (__half2*)(plane + (7168 + t) * 4);
            d[0] = __half2(__float2half(v7.x), __float2half(v7.y));
            d[1] = __half2(__float2half(v7.z), __float2half(v7.w));
        }
    }

    // ---- per-thread ROI tables (n = t), computed while staging drains ----
    float2 cc = ((const float2*)cand)[(size_t)b * NN + t];   // coalesced, L1
    unsigned int ypk[5], xpk[5];
    float Hy[5], Ly[5], Hx[5], Lx[5];
#pragma unroll
    for (int s = 0; s < 5; s++) {
        float fs = ((float)s + 0.5f) * 0.8f;   // identical assoc. to verified math

        // y-axis slot
        float y = (cc.y - 2.0f) + fs;
        float vy = ((y > -1.0f) && (y < (float)HH)) ? 1.0f : 0.0f;
        y = fmaxf(y, 0.0f);
        int y0 = (int)y;                       // y >= 0: trunc == floor
        bool ycl = (y0 >= HH - 1);
        if (ycl) y0 = HH - 1;
        int y1 = min(y0 + 1, HH - 1);
        float ly = ycl ? 0.0f : y - (float)y0;
        float hy = 1.0f - ly;
        ypk[s] = (unsigned int)(y0 * (WW * 2)) | ((unsigned int)(y1 * (WW * 2)) << 16);
        Hy[s] = vy * hy;                       // vy in {0,1}: products exact
        Ly[s] = vy * ly;

        // x-axis slot
        float x = (cc.x - 2.0f) + fs;
        float vx = ((x > -1.0f) && (x < (float)WW)) ? 1.0f : 0.0f;
        x = fmaxf(x, 0.0f);
        int x0 = (int)x;
        bool xcl = (x0 >= WW - 1);
        if (xcl) x0 = WW - 1;
        int x1 = min(x0 + 1, WW - 1);
        float lx = xcl ? 0.0f : x - (float)x0;
        float hx = 1.0f - lx;
        xpk[s] = (unsigned int)(x0 * 2) | ((unsigned int)(x1 * 2) << 16);
        Hx[s] = vx * hx;
        Lx[s] = vx * lx;
    }
    __syncthreads();

    const char* pl = (const char*)plane;
    float* op = out + ((size_t)b * NN + t) * (CCH * NPTS) + c * NPTS;  // 4B-aligned

    float q0 = 0.f, q1 = 0.f, q2 = 0.f;   // quad store buffer
#pragma unroll
    for (int k = 0; k < 24; k++) {
        const int py = k / 5, px = k - (k / 5) * 5;   // compile-time constants
        unsigned int yo = ypk[py], xo = xpk[px];
        unsigned int ry0 = yo & 0xffffu, ry1 = yo >> 16;
        unsigned int cx0 = xo & 0xffffu, cx1 = xo >> 16;

        float v00 = __half2float(*(const __half*)(pl + (ry0 + cx0)));
        float v01 = __half2float(*(const __half*)(pl + (ry0 + cx1)));
        float v10 = __half2float(*(const __half*)(pl + (ry1 + cx0)));
        float v11 = __half2float(*(const __half*)(pl + (ry1 + cx1)));

        float r = (Hy[py] * Hx[px]) * v00 + (Hy[py] * Lx[px]) * v01
                + (Ly[py] * Hx[px]) * v10 + (Ly[py] * Lx[px]) * v11;

        const int m = k & 3;
        if (m == 0)      q0 = r;
        else if (m == 1) q1 = r;
        else if (m == 2) q2 = r;
        else *(float4*)(op + (k - 3)) = make_float4(q0, q1, q2, r);
    }
    {   // k = 24 tail (py = 4, px = 4)
        unsigned int yo = ypk[4], xo = xpk[4];
        unsigned int ry0 = yo & 0xffffu, ry1 = yo >> 16;
        unsigned int cx0 = xo & 0xffffu, cx1 = xo >> 16;
        float v00 = __half2float(*(const __half*)(pl + (ry0 + cx0)));
        float v01 = __half2float(*(const __half*)(pl + (ry0 + cx1)));
        float v10 = __half2float(*(const __half*)(pl + (ry1 + cx0)));
        float v11 = __half2float(*(const __half*)(pl + (ry1 + cx1)));
        op[24] = (Hy[4] * Hx[4]) * v00 + (Hy[4] * Lx[4]) * v01
               + (Ly[4] * Hx[4]) * v10 + (Ly[4] * Lx[4]) * v11;
    }
}

extern "C" void kernel_launch(void* const* d_in, const int* in_sizes, int n_in,
                              void* d_out, int out_size, void* d_ws, size_t ws_size,
                              hipStream_t stream) {
    const float* fm   = (const float*)d_in[0];
    const float* cand = (const float*)d_in[1];
    float* out        = (float*)d_out;

    roi_nmajor<<<NB * CCH, 1024, 0, stream>>>(fm, cand, out);
}

// Round 5
// 485.623 us; speedup vs baseline: 1.0590x; 1.0590x over previous
//
#include <hip/hip_runtime.h>
#include <hip/hip_fp16.h>

#define NPTS 25          // 5*5
#define CCH 256
#define HH 135
#define WW 240
#define HWP (HH * WW)    // 32400
#define NV4 (HWP / 4)    // 8100 float4 per plane
#define NB 8
#define NN 1024

// ---------------------------------------------------------------------------
// One block per (b, c); 135x240 plane staged as fp16 in LDS (64,800 B ->
// 2 blocks/CU, 32 waves/CU). p-fast mapping (proven best store/gather
// pattern: conflicts 4.27M, WRITE 266MB).
//
// r0-r4 evidence: p-fast is at its VALU floor (~33 ops/pt compiled), but
// ~55% of cycles issue nothing -- the compiler emits a VGPR=20 serial
// schedule where each point's addr->4x ds_read_u16 (~120cy) ->cvt->fma->store
// chain is exposed. Fix: software-pipeline depth 1 -- issue point k's four
// LDS gathers FIRST, pin them with sched_barrier(0), then compute point
// k+1's sampling math (~60 VALU ops = ~120 cy, matching LDS latency), then
// consume k's gathers. The rotate keeps 4 gather regs + next-point state
// live, forcing a fatter schedule the r3 "ILP-2" attempt failed to get.
// ---------------------------------------------------------------------------

struct Pt { int o00, o01, o10, o11; float w00, w01, w10, w11; int oo; };

__device__ __forceinline__ Pt prep(const float2* __restrict__ cb2, int idx) {
    Pt r;
    int n  = (idx * 5243) >> 17;      // exact idx/25 for idx < 25600
    int p  = idx - n * 25;
    int py = (p * 205) >> 10;         // exact p/5 for p < 25
    int px = p - py * 5;

    float2 cc = cb2[n];               // L1-resident (8 KB per batch)

    // exact torchvision roi_align sampling math (identical to r0-verified)
    float y = (cc.y - 2.0f) + ((float)py + 0.5f) * 0.8f;
    float x = (cc.x - 2.0f) + ((float)px + 0.5f) * 0.8f;
    bool valid = (y > -1.0f) && (y < (float)HH) && (x > -1.0f) && (x < (float)WW);
    y = fmaxf(y, 0.0f);
    x = fmaxf(x, 0.0f);
    int y0 = (int)y;                  // y >= 0, trunc == floor
    int x0 = (int)x;
    bool yc = (y0 >= HH - 1);
    bool xc = (x0 >= WW - 1);
    if (yc) y0 = HH - 1;
    if (xc) x0 = WW - 1;
    int y1 = min(y0 + 1, HH - 1);
    int x1 = min(x0 + 1, WW - 1);
    float ly = yc ? 0.0f : y - (float)y0;
    float lx = xc ? 0.0f : x - (float)x0;
    float hy = 1.0f - ly, hx = 1.0f - lx;
    float vm = valid ? 1.0f : 0.0f;   // folded into weights: exact (x1.0/x0.0)

    int r0b = y0 * (WW * 2), r1b = y1 * (WW * 2);   // byte row offsets (fp16)
    r.o00 = r0b + x0 * 2; r.o01 = r0b + x1 * 2;
    r.o10 = r1b + x0 * 2; r.o11 = r1b + x1 * 2;
    float vhy = vm * hy, vly = vm * ly;
    r.w00 = vhy * hx; r.w01 = vhy * lx; r.w10 = vly * hx; r.w11 = vly * lx;
    r.oo = idx + n * 6375;            // n*6400 + p
    return r;
}

__global__ __launch_bounds__(1024, 8) void roi_plane_swp(const float* __restrict__ fm,
                                                         const float* __restrict__ cand,
                                                         float* __restrict__ out) {
    __shared__ __half plane[HWP];   // 64,800 bytes

    int blk = blockIdx.x;           // 0..2047
    int c   = blk & (CCH - 1);
    int b   = blk >> 8;
    int t   = threadIdx.x;          // 0..1023

    // ---- stage plane (b,c) into LDS as fp16 (r3-verified structure) ----
    const float4* src = (const float4*)(fm + ((size_t)b * CCH + c) * HWP);
    {
        float4 v0 = src[t];
        float4 v1 = src[1024 + t];
        float4 v2 = src[2048 + t];
        float4 v3 = src[3072 + t];
        __half2* d;
        d = (__half2*)(plane + (t) * 4);
        d[0] = __half2(__float2half(v0.x), __float2half(v0.y));
        d[1] = __half2(__float2half(v0.z), __float2half(v0.w));
        d = (__half2*)(plane + (1024 + t) * 4);
        d[0] = __half2(__float2half(v1.x), __float2half(v1.y));
        d[1] = __half2(__float2half(v1.z), __float2half(v1.w));
        d = (__half2*)(plane + (2048 + t) * 4);
        d[0] = __half2(__float2half(v2.x), __float2half(v2.y));
        d[1] = __half2(__float2half(v2.z), __float2half(v2.w));
        d = (__half2*)(plane + (3072 + t) * 4);
        d[0] = __half2(__float2half(v3.x), __float2half(v3.y));
        d[1] = __half2(__float2half(v3.z), __float2half(v3.w));

        float4 v4 = src[4096 + t];
        float4 v5 = src[5120 + t];
        float4 v6 = src[6144 + t];
        bool last = (t < NV4 - 7168);   // t < 932
        float4 v7 = last ? src[7168 + t] : make_float4(0.f, 0.f, 0.f, 0.f);
        d = (__half2*)(plane + (4096 + t) * 4);
        d[0] = __half2(__float2half(v4.x), __float2half(v4.y));
        d[1] = __half2(__float2half(v4.z), __float2half(v4.w));
        d = (__half2*)(plane + (5120 + t) * 4);
        d[0] = __half2(__float2half(v5.x), __float2half(v5.y));
        d[1] = __half2(__float2half(v5.z), __float2half(v5.w));
        d = (__half2*)(plane + (6144 + t) * 4);
        d[0] = __half2(__float2half(v6.x), __float2half(v6.y));
        d[1] = __half2(__float2half(v6.z), __float2half(v6.w));
        if (last) {
            d = (__half2*)(plane + (7168 + t) * 4);
            d[0] = __half2(__float2half(v7.x), __float2half(v7.y));
            d[1] = __half2(__float2half(v7.z), __float2half(v7.w));
        }
    }
    __syncthreads();

    const float2* cb2 = (const float2*)(cand + (size_t)b * NN * 2);
    float* obase = out + (size_t)b * NN * (CCH * NPTS) + c * NPTS;
    const char* pl = (const char*)plane;

    // ---- software-pipelined main loop, depth 1 ----
    Pt cur = prep(cb2, t);
#pragma unroll 1
    for (int k = 0; k < 24; k++) {
        // (1) issue the 4 LDS gathers for the CURRENT point first
        __half h00 = *(const __half*)(pl + cur.o00);
        __half h01 = *(const __half*)(pl + cur.o01);
        __half h10 = *(const __half*)(pl + cur.o10);
        __half h11 = *(const __half*)(pl + cur.o11);
        // pin: do not let the scheduler sink these loads below the prep math
        __builtin_amdgcn_sched_barrier(0);

        // (2) compute NEXT point's sampling math (~60 VALU ops ~ 120 cy,
        //     covering the ~120 cy ds_read latency of the gathers above)
        Pt nxt = prep(cb2, (k + 1) * 1024 + t);

        // (3) consume the gathers, store current result
        float v00 = __half2float(h00);
        float v01 = __half2float(h01);
        float v10 = __half2float(h10);
        float v11 = __half2float(h11);
        obase[cur.oo] = cur.w00 * v00 + cur.w01 * v01 + cur.w10 * v10 + cur.w11 * v11;

        cur = nxt;
    }
    {   // epilogue: last point (k = 24)
        float v00 = __half2float(*(const __half*)(pl + cur.o00));
        float v01 = __half2float(*(const __half*)(pl + cur.o01));
        float v10 = __half2float(*(const __half*)(pl + cur.o10));
        float v11 = __half2float(*(const __half*)(pl + cur.o11));
        obase[cur.oo] = cur.w00 * v00 + cur.w01 * v01 + cur.w10 * v10 + cur.w11 * v11;
    }
}

extern "C" void kernel_launch(void* const* d_in, const int* in_sizes, int n_in,
                              void* d_out, int out_size, void* d_ws, size_t ws_size,
                              hipStream_t stream) {
    const float* fm   = (const float*)d_in[0];
    const float* cand = (const float*)d_in[1];
    float* out        = (float*)d_out;

    roi_plane_swp<<<NB * CCH, 1024, 0, stream>>>(fm, cand, out);
}